// Round 7
// baseline (641.778 us; speedup 1.0000x reference)
//
#include <hip/hip_runtime.h>
#include <hip/hip_bf16.h>
#include <math.h>

#define B_   4
#define T_   2048
#define V_   512
#define D_   256
#define H_   4
#define DH_  64
#define NB_  32
#define DFF_ 1024
#define NL_  2

typedef __attribute__((ext_vector_type(8))) short short8_t;
typedef __attribute__((ext_vector_type(4))) float float4_t;
typedef __attribute__((ext_vector_type(4))) unsigned short ushort4_t;

#define MFMA16(a,b,c) __builtin_amdgcn_mfma_f32_16x16x32_bf16(a,b,c,0,0,0)
// fold softmax scale and log2(e) into Q so attention uses exp2 directly
#define QSCALE 0.18033688011112042f   // 0.125 * log2(e)

__device__ __forceinline__ unsigned short f2bf_bits(float f) {
    unsigned u = __float_as_uint(f);
    u += 0x7fffu + ((u >> 16) & 1u);
    return (unsigned short)(u >> 16);
}
__device__ __forceinline__ float bf2f(unsigned short u) {
    return __uint_as_float(((unsigned)u) << 16);
}

// ---------------------------------------------------------------------------
// Weight transpose+cast: W[K][N] fp32 -> Wt[N][K] bf16. One 32x32 tile/block.
// QKV packed into wqkvt[layer][768][256] (rows 0-255=Q^T,256-511=K^T,512-767=V^T)
// ---------------------------------------------------------------------------
__global__ __launch_bounds__(256) void wt_kernel(
    const float* __restrict__ Wq, const float* __restrict__ Wk,
    const float* __restrict__ Wv, const float* __restrict__ Wo,
    const float* __restrict__ W1, const float* __restrict__ W2,
    const float* __restrict__ Wout,
    unsigned short* __restrict__ wqkvt, unsigned short* __restrict__ wot,
    unsigned short* __restrict__ w1t, unsigned short* __restrict__ w2t,
    unsigned short* __restrict__ woutt)
{
    __shared__ float tile[32][33];
    int bx = blockIdx.x, tid = threadIdx.x;
    const float* src; unsigned short* dst; int Kd, Nd, tr, tc;
    if (bx < 512) {                    // Wq/Wk/Wv/Wo, 2 layers each, 256x256
        int am = bx >> 6, t = bx & 63;
        int mat = am >> 1, layer = am & 1;
        if (mat < 3) {
            const float* s3[3] = {Wq, Wk, Wv};
            src = s3[mat] + (long)layer * 65536;
            dst = wqkvt + (long)layer * 196608 + (long)mat * 65536;
        } else {
            src = Wo + (long)layer * 65536;
            dst = wot + (long)layer * 65536;
        }
        Kd = 256; Nd = 256; tr = t >> 3; tc = t & 7;
    } else if (bx < 1024) {            // W1: 2 x (256x1024)
        int idx = bx - 512, mat = idx >> 8, t = idx & 255;
        src = W1 + (long)mat * 262144; dst = w1t + (long)mat * 262144;
        Kd = 256; Nd = 1024; tr = t >> 5; tc = t & 31;
    } else if (bx < 1536) {            // W2: 2 x (1024x256)
        int idx = bx - 1024, mat = idx >> 8, t = idx & 255;
        src = W2 + (long)mat * 262144; dst = w2t + (long)mat * 262144;
        Kd = 1024; Nd = 256; tr = t >> 3; tc = t & 7;
    } else {                           // Wout: 256x512
        int t = bx - 1536;
        src = Wout; dst = woutt; Kd = 256; Nd = 512; tr = t >> 4; tc = t & 15;
    }
    int kr = tid >> 3, nc4 = (tid & 7) * 4;
    float4_t v = *(const float4_t*)&src[(long)(tr * 32 + kr) * Nd + tc * 32 + nc4];
    for (int j = 0; j < 4; ++j) tile[kr][nc4 + j] = v[j];
    __syncthreads();
    int nr = tid >> 3, kc4 = (tid & 7) * 4;
    unsigned short tmp[4];
    for (int j = 0; j < 4; ++j) tmp[j] = f2bf_bits(tile[kc4 + j][nr]);
    uint2 uu;
    uu.x = (unsigned)tmp[0] | ((unsigned)tmp[1] << 16);
    uu.y = (unsigned)tmp[2] | ((unsigned)tmp[3] << 16);
    *(uint2*)&dst[(long)(tc * 32 + nr) * Kd + tr * 32 + kc4] = uu;
}

// ---------------------------------------------------------------------------
// Token embedding gather + rank-2 delta projection
// ---------------------------------------------------------------------------
__global__ __launch_bounds__(256) void embed_kernel(
    const int* __restrict__ tokens, const float* __restrict__ emb,
    const float* __restrict__ w_in, const float* __restrict__ w_out,
    float* __restrict__ x, float* __restrict__ delta)
{
    int bt = blockIdx.x;
    int d  = threadIdx.x;
    int tok = tokens[bt];
    float e = emb[tok * D_ + d];
    x[(long)bt * D_ + d] = e;

    __shared__ float r0s[256], r1s[256];
    r0s[d] = e * w_in[d * 2 + 0];
    r1s[d] = e * w_in[d * 2 + 1];
    __syncthreads();
    for (int off = 128; off > 0; off >>= 1) {
        if (d < off) { r0s[d] += r0s[d + off]; r1s[d] += r1s[d + off]; }
        __syncthreads();
    }
    float r0 = r0s[0], r1 = r1s[0];
    if (d < H_ * NB_) {
        delta[(long)bt * (H_ * NB_) + d] =
            r0 * w_out[d] + r1 * w_out[H_ * NB_ + d];
    }
}

// ---------------------------------------------------------------------------
// cumsum over T per (b, channel) -> interleaved (cos,sin) float2
// ---------------------------------------------------------------------------
__global__ __launch_bounds__(256) void cumsum_kernel(
    const float* __restrict__ delta, const float* __restrict__ omega,
    float2* __restrict__ csb)
{
    int c = blockIdx.x & (H_ * NB_ - 1);
    int b = blockIdx.x >> 7;
    int tid = threadIdx.x;
    float om = omega[c];
    int h = c >> 5, nb = c & (NB_ - 1);

    float vals[8];
    float s = 0.0f;
    for (int i = 0; i < 8; ++i) {
        int t = tid * 8 + i;
        vals[i] = delta[((long)b * T_ + t) * (H_ * NB_) + c];
        s += vals[i];
    }
    __shared__ float sc[256];
    sc[tid] = s;
    __syncthreads();
    for (int off = 1; off < 256; off <<= 1) {
        float v = (tid >= off) ? sc[tid - off] : 0.0f;
        __syncthreads();
        sc[tid] += v;
        __syncthreads();
    }
    float run = sc[tid] - s;
    for (int i = 0; i < 8; ++i) {
        run += vals[i];
        float ang = run * om;
        int t = tid * 8 + i;
        long oi = ((long)(b * H_ + h) * T_ + t) * NB_ + nb;
        float2 cs; cs.x = cosf(ang); cs.y = sinf(ang);
        csb[oi] = cs;
    }
}

// ---------------------------------------------------------------------------
// LayerNorm (fp32 in) -> bf16 out; wave-shuffle reduction
// ---------------------------------------------------------------------------
__global__ __launch_bounds__(256) void ln_kernel(
    const float* __restrict__ x, const float* __restrict__ g,
    const float* __restrict__ b, unsigned short* __restrict__ out)
{
    int row = blockIdx.x;
    int d = threadIdx.x;
    int wv = d >> 6;
    float v = x[(long)row * D_ + d];
    float s = v, q = v * v;
    for (int off = 1; off < 64; off <<= 1) {
        s += __shfl_xor(s, off);
        q += __shfl_xor(q, off);
    }
    __shared__ float ps[4], pq[4];
    if ((d & 63) == 0) { ps[wv] = s; pq[wv] = q; }
    __syncthreads();
    s = ps[0] + ps[1] + ps[2] + ps[3];
    q = pq[0] + pq[1] + pq[2] + pq[3];
    float mu  = s * (1.0f / D_);
    float var = q * (1.0f / D_) - mu * mu;
    float inv = rsqrtf(var + 1e-5f);
    out[(long)row * D_ + d] = f2bf_bits((v - mu) * inv * g[d] + b[d]);
}

// ---------------------------------------------------------------------------
// Generic MFMA GEMM, 128xBN tile, BK=64, 4 waves.
// ---------------------------------------------------------------------------
template<int BN>
__global__ __launch_bounds__(256) void gemm_std(
    const unsigned short* __restrict__ A, const unsigned short* __restrict__ Bt,
    const float* __restrict__ bias, const float* __restrict__ res,
    float* __restrict__ outf, unsigned short* __restrict__ outb,
    int N, int K, int do_gelu)
{
    constexpr int RT = (BN == 128) ? 4 : 2;
    const float4_t ZERO4 = {0.f, 0.f, 0.f, 0.f};
    __shared__ __align__(16) short As[128 * 72];
    __shared__ __align__(16) short Bs[BN * 72];
    int tid = threadIdx.x;
    int w = tid >> 6, lane = tid & 63, quad = lane >> 4, l16 = lane & 15;
    int n0 = blockIdx.x * BN, r0 = blockIdx.y * 128;
    int rw = (BN == 128) ? (w & 1) * 64 : w * 32;
    int cw = (BN == 128) ? (w >> 1) * 64 : 0;

    float4_t acc[RT][4];
    for (int i = 0; i < RT; ++i)
        for (int j = 0; j < 4; ++j) acc[i][j] = ZERO4;

    for (int k0 = 0; k0 < K; k0 += 64) {
        __syncthreads();
        for (int p = 0; p < 4; ++p) {
            int e = tid + 256 * p;
            int r = e >> 3, c8 = e & 7;
            *(short8_t*)&As[r * 72 + c8 * 8] =
                *(const short8_t*)&A[(long)(r0 + r) * K + k0 + c8 * 8];
        }
        for (int p = 0; p < BN / 32; ++p) {
            int e = tid + 256 * p;
            int r = e >> 3, c8 = e & 7;
            *(short8_t*)&Bs[r * 72 + c8 * 8] =
                *(const short8_t*)&Bt[(long)(n0 + r) * K + k0 + c8 * 8];
        }
        __syncthreads();
        for (int kq = 0; kq < 2; ++kq) {
            short8_t a[RT];
            for (int i = 0; i < RT; ++i)
                a[i] = *(const short8_t*)&As[(rw + i * 16 + l16) * 72 + kq * 32 + quad * 8];
            for (int j = 0; j < 4; ++j) {
                short8_t bf = *(const short8_t*)&Bs[(cw + j * 16 + l16) * 72 + kq * 32 + quad * 8];
                for (int i = 0; i < RT; ++i)
                    acc[i][j] = MFMA16(a[i], bf, acc[i][j]);
            }
        }
    }

    for (int i = 0; i < RT; ++i) {
        for (int j = 0; j < 4; ++j) {
            int n = n0 + cw + j * 16 + l16;
            float bv = bias[n];
            for (int rr = 0; rr < 4; ++rr) {
                int row = r0 + rw + i * 16 + quad * 4 + rr;
                float v = acc[i][j][rr] + bv;
                if (res) v += res[(long)row * N + n];
                if (do_gelu) v = 0.5f * v * (1.0f + erff(v * 0.70710678118654752f));
                if (outb) outb[(long)row * N + n] = f2bf_bits(v);
                else      outf[(long)row * N + n] = v;
            }
        }
    }
}

// ---------------------------------------------------------------------------
// Fused QKV GEMM + bias + RoPE epilogue.
// Q: rope, pre-scaled by 0.125*log2e -> bf16 (B,H,T,DH)
// K: rope -> bf16 (B,H,T,DH)
// V: bf16 (B,H,DH,T) via packed 8-byte stores (4 consecutive t per frag reg)
// ---------------------------------------------------------------------------
__global__ __launch_bounds__(256) void gemm_qkv(
    const unsigned short* __restrict__ A, const unsigned short* __restrict__ Bt,
    const float* __restrict__ bq, const float* __restrict__ bk,
    const float* __restrict__ bv, const float2* __restrict__ csb,
    unsigned short* __restrict__ qb, unsigned short* __restrict__ kb,
    unsigned short* __restrict__ vt)
{
    const float4_t ZERO4 = {0.f, 0.f, 0.f, 0.f};
    __shared__ __align__(16) short As[128 * 72];
    __shared__ __align__(16) short Bs[128 * 72];
    int tid = threadIdx.x;
    int w = tid >> 6, lane = tid & 63, quad = lane >> 4, l16 = lane & 15;
    int n0 = blockIdx.x * 128, r0 = blockIdx.y * 128;
    int rw = (w & 1) * 64, cw = (w >> 1) * 64;

    float4_t acc[4][4];
    for (int i = 0; i < 4; ++i)
        for (int j = 0; j < 4; ++j) acc[i][j] = ZERO4;

    for (int k0 = 0; k0 < 256; k0 += 64) {
        __syncthreads();
        for (int p = 0; p < 4; ++p) {
            int e = tid + 256 * p;
            int r = e >> 3, c8 = e & 7;
            *(short8_t*)&As[r * 72 + c8 * 8] =
                *(const short8_t*)&A[(long)(r0 + r) * 256 + k0 + c8 * 8];
            *(short8_t*)&Bs[r * 72 + c8 * 8] =
                *(const short8_t*)&Bt[(long)(n0 + r) * 256 + k0 + c8 * 8];
        }
        __syncthreads();
        for (int kq = 0; kq < 2; ++kq) {
            short8_t a[4];
            for (int i = 0; i < 4; ++i)
                a[i] = *(const short8_t*)&As[(rw + i * 16 + l16) * 72 + kq * 32 + quad * 8];
            for (int j = 0; j < 4; ++j) {
                short8_t bf = *(const short8_t*)&Bs[(cw + j * 16 + l16) * 72 + kq * 32 + quad * 8];
                for (int i = 0; i < 4; ++i)
                    acc[i][j] = MFMA16(a[i], bf, acc[i][j]);
            }
        }
    }

    int nbase = n0 + cw;                 // 64-aligned, inside one part
    int part = nbase >> 8;               // 0=Q 1=K 2=V
    int hh = (nbase & 255) >> 6;
    int bconst = r0 >> 11;
    int tb = r0 & (T_ - 1);

    if (part < 2) {
        const float* biasp = (part == 0) ? bq : bk;
        unsigned short* qk = (part == 0) ? qb : kb;
        float scale = (part == 0) ? QSCALE : 1.0f;
        for (int i = 0; i < 4; ++i) {
            for (int j = 0; j < 4; ++j) {
                int dh = j * 16 + l16;
                float bvv = biasp[(nbase & 255) + dh];
                for (int rr = 0; rr < 4; ++rr) {
                    int t = tb + rw + i * 16 + quad * 4 + rr;
                    float v = acc[i][j][rr] + bvv;
                    float p = __shfl_xor(v, 1);
                    float2 cs = csb[((long)(bconst * H_ + hh) * T_ + t) * NB_ + (dh >> 1)];
                    float ov = (l16 & 1) ? (p * cs.y + v * cs.x)
                                         : (v * cs.x - p * cs.y);
                    qk[((long)(bconst * H_ + hh) * T_ + t) * DH_ + dh] =
                        f2bf_bits(ov * scale);
                }
            }
        }
    } else {
        for (int i = 0; i < 4; ++i) {
            for (int j = 0; j < 4; ++j) {
                int dh = j * 16 + l16;
                float bvv = bv[(nbase & 255) + dh];
                ushort4_t pk;
                for (int rr = 0; rr < 4; ++rr)
                    pk[rr] = f2bf_bits(acc[i][j][rr] + bvv);
                int t0 = tb + rw + i * 16 + quad * 4;
                *(ushort4_t*)&vt[((long)(bconst * H_ + hh) * DH_ + dh) * T_ + t0] = pk;
            }
        }
    }
}

// ---------------------------------------------------------------------------
// Split-K MFMA flash attention (partial pass). Block = 4 waves, 64 Q rows.
// grid (16 bh, 80 chunks); each chunk = up to 8 k-tiles (512 cols).
// Emits unnormalized partial O (bf16) + per-row m,l (fp32, base-2 domain).
// ---------------------------------------------------------------------------
__global__ __launch_bounds__(256) void attn_part(
    const unsigned short* __restrict__ Qb, const unsigned short* __restrict__ Kb,
    const unsigned short* __restrict__ Vt, unsigned short* __restrict__ po,
    float* __restrict__ pm, float* __restrict__ pl)
{
    const float4_t ZERO4 = {0.f, 0.f, 0.f, 0.f};
    __shared__ __align__(16) short Ps[4][16 * 72];

    int tid = threadIdx.x;
    int w = tid >> 6, lane = tid & 63;
    int quad = lane >> 4, l16 = lane & 15;
    int bh = blockIdx.x;
    int c  = blockIdx.y;
    int qt, kc;
    if (c < 8)       { qt = c;                kc = 0; }
    else if (c < 24) { qt = 8 + ((c - 8) >> 1);  kc = (c - 8) & 1; }
    else if (c < 48) { qt = 16 + (c - 24) / 3;   kc = (c - 24) % 3; }
    else             { qt = 24 + ((c - 48) >> 2); kc = (c - 48) & 3; }
    int q0 = qt * 64;
    int kt0 = kc * 8;
    int kt1 = (kt0 + 8 < qt + 1) ? kt0 + 8 : qt + 1;
    const long base = (long)bh * T_ * DH_;
    int qrow_lo = w * 16 + quad * 4;

    short8_t aq[2];
    {
        const unsigned short* qp = Qb + base + (long)(q0 + w * 16 + l16) * DH_;
        aq[0] = *(const short8_t*)(qp + quad * 8);
        aq[1] = *(const short8_t*)(qp + 32 + quad * 8);
    }

    float m_r[4], l_r[4];
    for (int r = 0; r < 4; ++r) { m_r[r] = -3.0e38f; l_r[r] = 0.0f; }
    float4_t o[4];
    for (int nt = 0; nt < 4; ++nt) o[nt] = ZERO4;

    for (int kt = kt0; kt < kt1; ++kt) {
        int k0 = kt * 64;

        short8_t vb[4][2];
        for (int nt = 0; nt < 4; ++nt) {
            const unsigned short* vp = Vt + base + (long)(nt * 16 + l16) * T_ + k0 + quad * 8;
            vb[nt][0] = *(const short8_t*)vp;
            vb[nt][1] = *(const short8_t*)(vp + 32);
        }

        float4_t s[4];
        for (int nt = 0; nt < 4; ++nt) {
            const unsigned short* kp = Kb + base + (long)(k0 + nt * 16 + l16) * DH_;
            short8_t kb0 = *(const short8_t*)(kp + quad * 8);
            short8_t kb1 = *(const short8_t*)(kp + 32 + quad * 8);
            float4_t t0 = MFMA16(aq[0], kb0, ZERO4);
            s[nt] = MFMA16(aq[1], kb1, t0);
        }

        if (kt == qt) {
            for (int nt = 0; nt < 4; ++nt) {
                int kcol = nt * 16 + l16;
                for (int r = 0; r < 4; ++r)
                    if (kcol > qrow_lo + r) s[nt][r] = -3.0e38f;
            }
        }

        float mt[4];
        for (int r = 0; r < 4; ++r)
            mt[r] = fmaxf(fmaxf(s[0][r], s[1][r]), fmaxf(s[2][r], s[3][r]));
        for (int off = 1; off < 16; off <<= 1)
            for (int r = 0; r < 4; ++r)
                mt[r] = fmaxf(mt[r], __shfl_xor(mt[r], off));

        float alpha[4];
        for (int r = 0; r < 4; ++r) {
            float mn = fmaxf(m_r[r], mt[r]);
            alpha[r] = __builtin_amdgcn_exp2f(m_r[r] - mn);
            m_r[r] = mn;
        }

        float lt[4] = {0.f, 0.f, 0.f, 0.f};
        for (int nt = 0; nt < 4; ++nt)
            for (int r = 0; r < 4; ++r) {
                float p = __builtin_amdgcn_exp2f(s[nt][r] - m_r[r]);
                lt[r] += p;
                Ps[w][(quad * 4 + r) * 72 + nt * 16 + l16] = (short)f2bf_bits(p);
            }
        for (int off = 1; off < 16; off <<= 1)
            for (int r = 0; r < 4; ++r)
                lt[r] += __shfl_xor(lt[r], off);
        for (int r = 0; r < 4; ++r) l_r[r] = l_r[r] * alpha[r] + lt[r];
        for (int nt = 0; nt < 4; ++nt)
            for (int r = 0; r < 4; ++r) o[nt][r] *= alpha[r];

        // O += P @ V  (wave-private strip, in-order DS pipe, no barrier)
        for (int kq = 0; kq < 2; ++kq) {
            short8_t pa = *(const short8_t*)&Ps[w][l16 * 72 + kq * 32 + quad * 8];
            for (int nt = 0; nt < 4; ++nt)
                o[nt] = MFMA16(pa, vb[nt][kq], o[nt]);
        }
    }

    int slot = (bh * 32 + qt) * 4 + kc;
    unsigned short* pop = po + (long)slot * 4096;
    for (int r = 0; r < 4; ++r)
        for (int nt = 0; nt < 4; ++nt)
            pop[(qrow_lo + r) * 64 + nt * 16 + l16] = f2bf_bits(o[nt][r]);
    if (l16 == 0) {
        for (int r = 0; r < 4; ++r) {
            pm[slot * 64 + qrow_lo + r] = m_r[r];
            pl[slot * 64 + qrow_lo + r] = l_r[r];
        }
    }
}

// ---------------------------------------------------------------------------
// Combine partials: O = (sum_i po_i*2^(m_i-M)) / (sum_i l_i*2^(m_i-M))
// grid 512 = (bh,qt); thread -> (row=tid/4, 16-dh chunk).
// Writes obuf bf16 row-major (b,t,h,dh).
// ---------------------------------------------------------------------------
__global__ __launch_bounds__(256) void attn_comb(
    const unsigned short* __restrict__ po, const float* __restrict__ pm,
    const float* __restrict__ pl, unsigned short* __restrict__ O)
{
    int bh = blockIdx.x & 15, qt = blockIdx.x >> 4;
    int nc = (qt >> 3) + 1;
    int tid = threadIdx.x;
    int row = tid >> 2;
    int dh0 = (tid & 3) << 4;
    int slot0 = (bh * 32 + qt) * 4;

    float mv[4], wgt[4];
    float M = -3.0e38f;
    for (int i = 0; i < nc; ++i) {
        mv[i] = pm[(slot0 + i) * 64 + row];
        M = fmaxf(M, mv[i]);
    }
    float L = 0.f;
    for (int i = 0; i < nc; ++i) {
        wgt[i] = __builtin_amdgcn_exp2f(mv[i] - M);
        L += pl[(slot0 + i) * 64 + row] * wgt[i];
    }
    float invL = 1.0f / L;

    int b = bh >> 2, h = bh & 3;
    int t = qt * 64 + row;
    long ob = ((long)b * T_ + t) * D_ + h * DH_ + dh0;
    for (int d = 0; d < 16; ++d) {
        float acc = 0.f;
        for (int i = 0; i < nc; ++i)
            acc += bf2f(po[(long)(slot0 + i) * 4096 + row * 64 + dh0 + d]) * wgt[i];
        O[ob + d] = f2bf_bits(acc * invL);
    }
}

// ---------------------------------------------------------------------------
extern "C" void kernel_launch(void* const* d_in, const int* in_sizes, int n_in,
                              void* d_out, int out_size, void* d_ws, size_t ws_size,
                              hipStream_t stream)
{
    const int*   tokens    = (const int*)d_in[0];
    const float* token_emb = (const float*)d_in[1];
    const float* w_in      = (const float*)d_in[2];
    const float* w_out     = (const float*)d_in[3];
    const float* omega     = (const float*)d_in[4];
    const float* Wq        = (const float*)d_in[5];
    const float* bq        = (const float*)d_in[6];
    const float* Wk        = (const float*)d_in[7];
    const float* bk        = (const float*)d_in[8];
    const float* Wv        = (const float*)d_in[9];
    const float* bv        = (const float*)d_in[10];
    const float* Wo        = (const float*)d_in[11];
    const float* bo        = (const float*)d_in[12];
    const float* ln1_g     = (const float*)d_in[13];
    const float* ln1_b     = (const float*)d_in[14];
    const float* ln2_g     = (const float*)d_in[15];
    const float* ln2_b     = (const float*)d_in[16];
    const float* W1        = (const float*)d_in[17];
    const float* b1        = (const float*)d_in[18];
    const float* W2        = (const float*)d_in[19];
    const float* b2        = (const float*)d_in[20];
    const float* out_g     = (const float*)d_in[21];
    const float* out_b     = (const float*)d_in[22];
    const float* Wout      = (const float*)d_in[23];
    const float* bout      = (const float*)d_in[24];

    const long NTOK = (long)B_ * T_;  // 8192
    float*  xbuf = (float*)d_ws;                         // fp32 residual (8 MB)
    float*  dbuf = xbuf + NTOK * D_;                     // (B,T,H*NB) fp32 (4 MB)
    float2* csb  = (float2*)(dbuf + NTOK * H_ * NB_);    // (B,H,T,NB) cos/sin (8 MB)
    unsigned short* hbuf  = (unsigned short*)(csb + NTOK * H_ * NB_); // LN out bf16
    unsigned short* qb    = hbuf + NTOK * D_;            // (B,H,T,DH) bf16
    unsigned short* kb    = qb + NTOK * D_;
    unsigned short* vt    = kb + NTOK * D_;              // (B,H,DH,T) bf16
    unsigned short* obuf  = vt + NTOK * D_;              // attn out bf16 row-major
    unsigned short* ffbuf = obuf + NTOK * D_;            // FFN mid bf16 (16 MB)
    unsigned short* pobuf = ffbuf;                       // attn partials alias ffbuf
    unsigned short* wqkvt = ffbuf + NTOK * DFF_;         // [2][768][256]
    unsigned short* wot   = wqkvt + 2 * 768 * 256;
    unsigned short* w1t   = wot + 2 * 65536;
    unsigned short* w2t   = w1t + 2 * 262144;
    unsigned short* woutt = w2t + 2 * 262144;
    float* pmbuf = (float*)(woutt + V_ * D_);            // [16*32*4][64] fp32
    float* plbuf = pmbuf + 16 * 32 * 4 * 64;
    // total ~61 MB

    wt_kernel<<<1664, 256, 0, stream>>>(Wq, Wk, Wv, Wo, W1, W2, Wout,
                                        wqkvt, wot, w1t, w2t, woutt);
    embed_kernel<<<NTOK, 256, 0, stream>>>(tokens, token_emb, w_in, w_out, xbuf, dbuf);
    cumsum_kernel<<<B_ * H_ * NB_, 256, 0, stream>>>(dbuf, omega, csb);

    for (int l = 0; l < NL_; ++l) {
        ln_kernel<<<NTOK, 256, 0, stream>>>(xbuf, ln1_g + l * D_, ln1_b + l * D_, hbuf);
        gemm_qkv<<<dim3(6, 64), 256, 0, stream>>>(
            hbuf, wqkvt + (long)l * 196608, bq + l * D_, bk + l * D_, bv + l * D_,
            csb, qb, kb, vt);
        attn_part<<<dim3(16, 80), 256, 0, stream>>>(qb, kb, vt, pobuf, pmbuf, plbuf);
        attn_comb<<<512, 256, 0, stream>>>(pobuf, pmbuf, plbuf, obuf);
        gemm_std<64><<<dim3(4, 64), 256, 0, stream>>>(
            obuf, wot + (long)l * 65536, bo + l * D_, xbuf, xbuf, nullptr,
            D_, D_, 0);
        ln_kernel<<<NTOK, 256, 0, stream>>>(xbuf, ln2_g + l * D_, ln2_b + l * D_, hbuf);
        gemm_std<128><<<dim3(8, 64), 256, 0, stream>>>(
            hbuf, w1t + (long)l * 262144, b1 + l * DFF_, nullptr, nullptr, ffbuf,
            DFF_, D_, 1);
        gemm_std<64><<<dim3(4, 64), 256, 0, stream>>>(
            ffbuf, w2t + (long)l * 262144, b2 + l * D_, xbuf, xbuf, nullptr,
            D_, DFF_, 0);
    }

    ln_kernel<<<NTOK, 256, 0, stream>>>(xbuf, out_g, out_b, hbuf);
    gemm_std<128><<<dim3(4, 64), 256, 0, stream>>>(
        hbuf, woutt, bout, nullptr, (float*)d_out, nullptr,
        V_, D_, 0);
}

// Round 8
// 563.168 us; speedup vs baseline: 1.1396x; 1.1396x over previous
//
#include <hip/hip_runtime.h>
#include <hip/hip_bf16.h>
#include <math.h>

#define B_   4
#define T_   2048
#define V_   512
#define D_   256
#define H_   4
#define DH_  64
#define NB_  32
#define DFF_ 1024
#define NL_  2

typedef __attribute__((ext_vector_type(8))) short short8_t;
typedef __attribute__((ext_vector_type(4))) float float4_t;
typedef __attribute__((ext_vector_type(4))) unsigned short ushort4_t;

#define MFMA16(a,b,c) __builtin_amdgcn_mfma_f32_16x16x32_bf16(a,b,c,0,0,0)
// fold softmax scale and log2(e) into Q so attention uses exp2 directly
#define QSCALE 0.18033688011112042f   // 0.125 * log2(e)

__device__ __forceinline__ unsigned short f2bf_bits(float f) {
    unsigned u = __float_as_uint(f);
    u += 0x7fffu + ((u >> 16) & 1u);
    return (unsigned short)(u >> 16);
}

// 16-lane (DPP-row) max reduction, pure VALU (no LDS pipe)
template<int CTRL>
__device__ __forceinline__ float fmax_dpp(float a) {
    int t = __builtin_amdgcn_update_dpp(0, __float_as_int(a), CTRL, 0xF, 0xF, true);
    return fmaxf(a, __int_as_float(t));
}
__device__ __forceinline__ float max16(float x) {
    x = fmax_dpp<0xB1>(x);   // quad_perm [1,0,3,2]  (xor 1)
    x = fmax_dpp<0x4E>(x);   // quad_perm [2,3,0,1]  (xor 2)
    x = fmax_dpp<0x141>(x);  // row_half_mirror      (pairs 4-groups)
    x = fmax_dpp<0x140>(x);  // row_mirror           (pairs 8-groups)
    return x;
}

// ---------------------------------------------------------------------------
// Weight transpose+cast: W[K][N] fp32 -> Wt[N][K] bf16. One 32x32 tile/block.
// QKV packed into wqkvt[layer][768][256] (rows 0-255=Q^T,256-511=K^T,512-767=V^T)
// ---------------------------------------------------------------------------
__global__ __launch_bounds__(256) void wt_kernel(
    const float* __restrict__ Wq, const float* __restrict__ Wk,
    const float* __restrict__ Wv, const float* __restrict__ Wo,
    const float* __restrict__ W1, const float* __restrict__ W2,
    const float* __restrict__ Wout,
    unsigned short* __restrict__ wqkvt, unsigned short* __restrict__ wot,
    unsigned short* __restrict__ w1t, unsigned short* __restrict__ w2t,
    unsigned short* __restrict__ woutt)
{
    __shared__ float tile[32][33];
    int bx = blockIdx.x, tid = threadIdx.x;
    const float* src; unsigned short* dst; int Kd, Nd, tr, tc;
    if (bx < 512) {                    // Wq/Wk/Wv/Wo, 2 layers each, 256x256
        int am = bx >> 6, t = bx & 63;
        int mat = am >> 1, layer = am & 1;
        if (mat < 3) {
            const float* s3[3] = {Wq, Wk, Wv};
            src = s3[mat] + (long)layer * 65536;
            dst = wqkvt + (long)layer * 196608 + (long)mat * 65536;
        } else {
            src = Wo + (long)layer * 65536;
            dst = wot + (long)layer * 65536;
        }
        Kd = 256; Nd = 256; tr = t >> 3; tc = t & 7;
    } else if (bx < 1024) {            // W1: 2 x (256x1024)
        int idx = bx - 512, mat = idx >> 8, t = idx & 255;
        src = W1 + (long)mat * 262144; dst = w1t + (long)mat * 262144;
        Kd = 256; Nd = 1024; tr = t >> 5; tc = t & 31;
    } else if (bx < 1536) {            // W2: 2 x (1024x256)
        int idx = bx - 1024, mat = idx >> 8, t = idx & 255;
        src = W2 + (long)mat * 262144; dst = w2t + (long)mat * 262144;
        Kd = 1024; Nd = 256; tr = t >> 3; tc = t & 7;
    } else {                           // Wout: 256x512
        int t = bx - 1536;
        src = Wout; dst = woutt; Kd = 256; Nd = 512; tr = t >> 4; tc = t & 15;
    }
    int kr = tid >> 3, nc4 = (tid & 7) * 4;
    float4_t v = *(const float4_t*)&src[(long)(tr * 32 + kr) * Nd + tc * 32 + nc4];
    for (int j = 0; j < 4; ++j) tile[kr][nc4 + j] = v[j];
    __syncthreads();
    int nr = tid >> 3, kc4 = (tid & 7) * 4;
    unsigned short tmp[4];
    for (int j = 0; j < 4; ++j) tmp[j] = f2bf_bits(tile[kc4 + j][nr]);
    uint2 uu;
    uu.x = (unsigned)tmp[0] | ((unsigned)tmp[1] << 16);
    uu.y = (unsigned)tmp[2] | ((unsigned)tmp[3] << 16);
    *(uint2*)&dst[(long)(tc * 32 + nr) * Kd + tr * 32 + kc4] = uu;
}

// ---------------------------------------------------------------------------
// Token embedding gather + rank-2 delta projection
// ---------------------------------------------------------------------------
__global__ __launch_bounds__(256) void embed_kernel(
    const int* __restrict__ tokens, const float* __restrict__ emb,
    const float* __restrict__ w_in, const float* __restrict__ w_out,
    float* __restrict__ x, float* __restrict__ delta)
{
    int bt = blockIdx.x;
    int d  = threadIdx.x;
    int tok = tokens[bt];
    float e = emb[tok * D_ + d];
    x[(long)bt * D_ + d] = e;

    __shared__ float r0s[256], r1s[256];
    r0s[d] = e * w_in[d * 2 + 0];
    r1s[d] = e * w_in[d * 2 + 1];
    __syncthreads();
    for (int off = 128; off > 0; off >>= 1) {
        if (d < off) { r0s[d] += r0s[d + off]; r1s[d] += r1s[d + off]; }
        __syncthreads();
    }
    float r0 = r0s[0], r1 = r1s[0];
    if (d < H_ * NB_) {
        delta[(long)bt * (H_ * NB_) + d] =
            r0 * w_out[d] + r1 * w_out[H_ * NB_ + d];
    }
}

// ---------------------------------------------------------------------------
// cumsum over T per (b, channel) -> interleaved (cos,sin) float2
// ---------------------------------------------------------------------------
__global__ __launch_bounds__(256) void cumsum_kernel(
    const float* __restrict__ delta, const float* __restrict__ omega,
    float2* __restrict__ csb)
{
    int c = blockIdx.x & (H_ * NB_ - 1);
    int b = blockIdx.x >> 7;
    int tid = threadIdx.x;
    float om = omega[c];
    int h = c >> 5, nb = c & (NB_ - 1);

    float vals[8];
    float s = 0.0f;
    for (int i = 0; i < 8; ++i) {
        int t = tid * 8 + i;
        vals[i] = delta[((long)b * T_ + t) * (H_ * NB_) + c];
        s += vals[i];
    }
    __shared__ float sc[256];
    sc[tid] = s;
    __syncthreads();
    for (int off = 1; off < 256; off <<= 1) {
        float v = (tid >= off) ? sc[tid - off] : 0.0f;
        __syncthreads();
        sc[tid] += v;
        __syncthreads();
    }
    float run = sc[tid] - s;
    for (int i = 0; i < 8; ++i) {
        run += vals[i];
        float ang = run * om;
        int t = tid * 8 + i;
        long oi = ((long)(b * H_ + h) * T_ + t) * NB_ + nb;
        float2 cs; cs.x = cosf(ang); cs.y = sinf(ang);
        csb[oi] = cs;
    }
}

// ---------------------------------------------------------------------------
// LayerNorm (fp32 in) -> bf16 out; wave-shuffle reduction
// ---------------------------------------------------------------------------
__global__ __launch_bounds__(256) void ln_kernel(
    const float* __restrict__ x, const float* __restrict__ g,
    const float* __restrict__ b, unsigned short* __restrict__ out)
{
    int row = blockIdx.x;
    int d = threadIdx.x;
    int wv = d >> 6;
    float v = x[(long)row * D_ + d];
    float s = v, q = v * v;
    for (int off = 1; off < 64; off <<= 1) {
        s += __shfl_xor(s, off);
        q += __shfl_xor(q, off);
    }
    __shared__ float ps[4], pq[4];
    if ((d & 63) == 0) { ps[wv] = s; pq[wv] = q; }
    __syncthreads();
    s = ps[0] + ps[1] + ps[2] + ps[3];
    q = pq[0] + pq[1] + pq[2] + pq[3];
    float mu  = s * (1.0f / D_);
    float var = q * (1.0f / D_) - mu * mu;
    float inv = rsqrtf(var + 1e-5f);
    out[(long)row * D_ + d] = f2bf_bits((v - mu) * inv * g[d] + b[d]);
}

// ---------------------------------------------------------------------------
// Generic MFMA GEMM, 128xBN tile, BK=64, 4 waves.
// ---------------------------------------------------------------------------
template<int BN>
__global__ __launch_bounds__(256) void gemm_std(
    const unsigned short* __restrict__ A, const unsigned short* __restrict__ Bt,
    const float* __restrict__ bias, const float* __restrict__ res,
    float* __restrict__ outf, unsigned short* __restrict__ outb,
    int N, int K, int do_gelu)
{
    constexpr int RT = (BN == 128) ? 4 : 2;
    const float4_t ZERO4 = {0.f, 0.f, 0.f, 0.f};
    __shared__ __align__(16) short As[128 * 72];
    __shared__ __align__(16) short Bs[BN * 72];
    int tid = threadIdx.x;
    int w = tid >> 6, lane = tid & 63, quad = lane >> 4, l16 = lane & 15;
    int n0 = blockIdx.x * BN, r0 = blockIdx.y * 128;
    int rw = (BN == 128) ? (w & 1) * 64 : w * 32;
    int cw = (BN == 128) ? (w >> 1) * 64 : 0;

    float4_t acc[RT][4];
    for (int i = 0; i < RT; ++i)
        for (int j = 0; j < 4; ++j) acc[i][j] = ZERO4;

    for (int k0 = 0; k0 < K; k0 += 64) {
        __syncthreads();
        for (int p = 0; p < 4; ++p) {
            int e = tid + 256 * p;
            int r = e >> 3, c8 = e & 7;
            *(short8_t*)&As[r * 72 + c8 * 8] =
                *(const short8_t*)&A[(long)(r0 + r) * K + k0 + c8 * 8];
        }
        for (int p = 0; p < BN / 32; ++p) {
            int e = tid + 256 * p;
            int r = e >> 3, c8 = e & 7;
            *(short8_t*)&Bs[r * 72 + c8 * 8] =
                *(const short8_t*)&Bt[(long)(n0 + r) * K + k0 + c8 * 8];
        }
        __syncthreads();
        for (int kq = 0; kq < 2; ++kq) {
            short8_t a[RT];
            for (int i = 0; i < RT; ++i)
                a[i] = *(const short8_t*)&As[(rw + i * 16 + l16) * 72 + kq * 32 + quad * 8];
            for (int j = 0; j < 4; ++j) {
                short8_t bf = *(const short8_t*)&Bs[(cw + j * 16 + l16) * 72 + kq * 32 + quad * 8];
                for (int i = 0; i < RT; ++i)
                    acc[i][j] = MFMA16(a[i], bf, acc[i][j]);
            }
        }
    }

    for (int i = 0; i < RT; ++i) {
        for (int j = 0; j < 4; ++j) {
            int n = n0 + cw + j * 16 + l16;
            float bv = bias[n];
            for (int rr = 0; rr < 4; ++rr) {
                int row = r0 + rw + i * 16 + quad * 4 + rr;
                float v = acc[i][j][rr] + bv;
                if (res) v += res[(long)row * N + n];
                if (do_gelu) v = 0.5f * v * (1.0f + erff(v * 0.70710678118654752f));
                if (outb) outb[(long)row * N + n] = f2bf_bits(v);
                else      outf[(long)row * N + n] = v;
            }
        }
    }
}

// ---------------------------------------------------------------------------
// Fused QKV GEMM + bias + RoPE epilogue.
// Q: rope, pre-scaled by 0.125*log2e -> bf16 (B,H,T,DH)
// K: rope -> bf16 (B,H,T,DH)
// V: bf16 (B,H,DH,T) via packed 8-byte stores (4 consecutive t per frag reg)
// ---------------------------------------------------------------------------
__global__ __launch_bounds__(256) void gemm_qkv(
    const unsigned short* __restrict__ A, const unsigned short* __restrict__ Bt,
    const float* __restrict__ bq, const float* __restrict__ bk,
    const float* __restrict__ bv, const float2* __restrict__ csb,
    unsigned short* __restrict__ qb, unsigned short* __restrict__ kb,
    unsigned short* __restrict__ vt)
{
    const float4_t ZERO4 = {0.f, 0.f, 0.f, 0.f};
    __shared__ __align__(16) short As[128 * 72];
    __shared__ __align__(16) short Bs[128 * 72];
    int tid = threadIdx.x;
    int w = tid >> 6, lane = tid & 63, quad = lane >> 4, l16 = lane & 15;
    int n0 = blockIdx.x * 128, r0 = blockIdx.y * 128;
    int rw = (w & 1) * 64, cw = (w >> 1) * 64;

    float4_t acc[4][4];
    for (int i = 0; i < 4; ++i)
        for (int j = 0; j < 4; ++j) acc[i][j] = ZERO4;

    for (int k0 = 0; k0 < 256; k0 += 64) {
        __syncthreads();
        for (int p = 0; p < 4; ++p) {
            int e = tid + 256 * p;
            int r = e >> 3, c8 = e & 7;
            *(short8_t*)&As[r * 72 + c8 * 8] =
                *(const short8_t*)&A[(long)(r0 + r) * 256 + k0 + c8 * 8];
            *(short8_t*)&Bs[r * 72 + c8 * 8] =
                *(const short8_t*)&Bt[(long)(n0 + r) * 256 + k0 + c8 * 8];
        }
        __syncthreads();
        for (int kq = 0; kq < 2; ++kq) {
            short8_t a[4];
            for (int i = 0; i < 4; ++i)
                a[i] = *(const short8_t*)&As[(rw + i * 16 + l16) * 72 + kq * 32 + quad * 8];
            for (int j = 0; j < 4; ++j) {
                short8_t bf = *(const short8_t*)&Bs[(cw + j * 16 + l16) * 72 + kq * 32 + quad * 8];
                for (int i = 0; i < 4; ++i)
                    acc[i][j] = MFMA16(a[i], bf, acc[i][j]);
            }
        }
    }

    int nbase = n0 + cw;                 // 64-aligned, inside one part
    int part = nbase >> 8;               // 0=Q 1=K 2=V
    int hh = (nbase & 255) >> 6;
    int bconst = r0 >> 11;
    int tb = r0 & (T_ - 1);

    if (part < 2) {
        const float* biasp = (part == 0) ? bq : bk;
        unsigned short* qk = (part == 0) ? qb : kb;
        float scale = (part == 0) ? QSCALE : 1.0f;
        for (int i = 0; i < 4; ++i) {
            for (int j = 0; j < 4; ++j) {
                int dh = j * 16 + l16;
                float bvv = biasp[(nbase & 255) + dh];
                for (int rr = 0; rr < 4; ++rr) {
                    int t = tb + rw + i * 16 + quad * 4 + rr;
                    float v = acc[i][j][rr] + bvv;
                    float p = __shfl_xor(v, 1);
                    float2 cs = csb[((long)(bconst * H_ + hh) * T_ + t) * NB_ + (dh >> 1)];
                    float ov = (l16 & 1) ? (p * cs.y + v * cs.x)
                                         : (v * cs.x - p * cs.y);
                    qk[((long)(bconst * H_ + hh) * T_ + t) * DH_ + dh] =
                        f2bf_bits(ov * scale);
                }
            }
        }
    } else {
        for (int i = 0; i < 4; ++i) {
            for (int j = 0; j < 4; ++j) {
                int dh = j * 16 + l16;
                float bvv = bv[(nbase & 255) + dh];
                ushort4_t pk;
                for (int rr = 0; rr < 4; ++rr)
                    pk[rr] = f2bf_bits(acc[i][j][rr] + bvv);
                int t0 = tb + rw + i * 16 + quad * 4;
                *(ushort4_t*)&vt[((long)(bconst * H_ + hh) * DH_ + dh) * T_ + t0] = pk;
            }
        }
    }
}

// ---------------------------------------------------------------------------
// MFMA flash attention, monolithic (r5 structure), latency-tuned:
// - K prefetched one tile ahead into registers (2-phase unroll)
// - 16-lane row max via DPP (VALU) instead of shuffles (LDS pipe)
// - row-sum l via ones-column MFMA (no sum shuffles)
// - exp2-domain softmax (Q pre-scaled by 0.125*log2e)
// O written bf16 row-major (b,t,h,dh) = [8192][256].
// ---------------------------------------------------------------------------
__global__ __launch_bounds__(256) void attn_mfma(
    const unsigned short* __restrict__ Qb, const unsigned short* __restrict__ Kb,
    const unsigned short* __restrict__ Vt, unsigned short* __restrict__ O)
{
    const float4_t ZERO4 = {0.f, 0.f, 0.f, 0.f};
    __shared__ __align__(16) short Ps[4][16 * 72];

    int tid = threadIdx.x;
    int w = tid >> 6, lane = tid & 63;
    int quad = lane >> 4, l16 = lane & 15;
    int bh = blockIdx.x & 15;           // bh%8 -> XCD affinity for K/V L2 reuse
    int qi = blockIdx.x >> 4;
    int qt = (qi < 16) ? qi : 47 - qi;  // pair qt with 31-qt for CU balance
    int q0 = qt * 64;
    const long base = (long)bh * T_ * DH_;
    int qrow_lo = w * 16 + quad * 4;

    short8_t aq[2];
    {
        const unsigned short* qp = Qb + base + (long)(q0 + w * 16 + l16) * DH_;
        aq[0] = *(const short8_t*)(qp + quad * 8);
        aq[1] = *(const short8_t*)(qp + 32 + quad * 8);
    }
    short8_t bones;
    for (int j = 0; j < 8; ++j) bones[j] = (short)0x3F80;  // bf16 1.0

    float m_r[4];
    for (int r = 0; r < 4; ++r) m_r[r] = -3.0e38f;
    float4_t l4 = ZERO4;
    float4_t o[4];
    for (int nt = 0; nt < 4; ++nt) o[nt] = ZERO4;

    short8_t kA[4][2], kB[4][2];

    auto loadK = [&](int k0, short8_t (&kd)[4][2]) {
        for (int nt = 0; nt < 4; ++nt) {
            const unsigned short* kp = Kb + base + (long)(k0 + nt * 16 + l16) * DH_;
            kd[nt][0] = *(const short8_t*)(kp + quad * 8);
            kd[nt][1] = *(const short8_t*)(kp + 32 + quad * 8);
        }
    };

    auto process = [&](int k0, short8_t (&kd)[4][2], bool diag) {
        // V loads issued first; consumed only at PV (hidden by S+softmax)
        short8_t vb[4][2];
        for (int nt = 0; nt < 4; ++nt) {
            const unsigned short* vp = Vt + base + (long)(nt * 16 + l16) * T_ + k0 + quad * 8;
            vb[nt][0] = *(const short8_t*)vp;
            vb[nt][1] = *(const short8_t*)(vp + 32);
        }

        float4_t s[4];
        for (int nt = 0; nt < 4; ++nt) {
            float4_t t0 = MFMA16(aq[0], kd[nt][0], ZERO4);
            s[nt] = MFMA16(aq[1], kd[nt][1], t0);
        }

        if (diag) {
            for (int nt = 0; nt < 4; ++nt) {
                int kcol = nt * 16 + l16;
                for (int r = 0; r < 4; ++r)
                    if (kcol > qrow_lo + r) s[nt][r] = -3.0e38f;
            }
        }

        float alpha[4];
        for (int r = 0; r < 4; ++r) {
            float mt = fmaxf(fmaxf(s[0][r], s[1][r]), fmaxf(s[2][r], s[3][r]));
            mt = max16(mt);
            float mn = fmaxf(m_r[r], mt);
            alpha[r] = __builtin_amdgcn_exp2f(m_r[r] - mn);
            m_r[r] = mn;
        }

        for (int nt = 0; nt < 4; ++nt)
            for (int r = 0; r < 4; ++r) {
                float p = __builtin_amdgcn_exp2f(s[nt][r] - m_r[r]);
                Ps[w][(quad * 4 + r) * 72 + nt * 16 + l16] = (short)f2bf_bits(p);
            }

        for (int nt = 0; nt < 4; ++nt)
            for (int r = 0; r < 4; ++r) o[nt][r] *= alpha[r];
        for (int r = 0; r < 4; ++r) l4[r] *= alpha[r];

        // O += P @ V ; l += P @ 1  (wave-private strip, in-order DS pipe)
        for (int kq = 0; kq < 2; ++kq) {
            short8_t pa = *(const short8_t*)&Ps[w][l16 * 72 + kq * 32 + quad * 8];
            for (int nt = 0; nt < 4; ++nt)
                o[nt] = MFMA16(pa, vb[nt][kq], o[nt]);
            l4 = MFMA16(pa, bones, l4);
        }
    };

    // 2-phase K-prefetch pipeline
    loadK(0, kA);
    int kt = 0;
    while (true) {
        if (kt + 1 <= qt) loadK((kt + 1) * 64, kB);
        process(kt * 64, kA, kt == qt);
        ++kt; if (kt > qt) break;
        if (kt + 1 <= qt) loadK((kt + 1) * 64, kA);
        process(kt * 64, kB, kt == qt);
        ++kt; if (kt > qt) break;
    }

    int b = bh >> 2, h = bh & 3;
    for (int r = 0; r < 4; ++r) {
        float inv = 1.0f / l4[r];
        int trow = q0 + w * 16 + quad * 4 + r;
        long orow = ((long)b * T_ + trow) * D_ + h * DH_;
        for (int nt = 0; nt < 4; ++nt)
            O[orow + nt * 16 + l16] = f2bf_bits(o[nt][r] * inv);
    }
}

// ---------------------------------------------------------------------------
extern "C" void kernel_launch(void* const* d_in, const int* in_sizes, int n_in,
                              void* d_out, int out_size, void* d_ws, size_t ws_size,
                              hipStream_t stream)
{
    const int*   tokens    = (const int*)d_in[0];
    const float* token_emb = (const float*)d_in[1];
    const float* w_in      = (const float*)d_in[2];
    const float* w_out     = (const float*)d_in[3];
    const float* omega     = (const float*)d_in[4];
    const float* Wq        = (const float*)d_in[5];
    const float* bq        = (const float*)d_in[6];
    const float* Wk        = (const float*)d_in[7];
    const float* bk        = (const float*)d_in[8];
    const float* Wv        = (const float*)d_in[9];
    const float* bv        = (const float*)d_in[10];
    const float* Wo        = (const float*)d_in[11];
    const float* bo        = (const float*)d_in[12];
    const float* ln1_g     = (const float*)d_in[13];
    const float* ln1_b     = (const float*)d_in[14];
    const float* ln2_g     = (const float*)d_in[15];
    const float* ln2_b     = (const float*)d_in[16];
    const float* W1        = (const float*)d_in[17];
    const float* b1        = (const float*)d_in[18];
    const float* W2        = (const float*)d_in[19];
    const float* b2        = (const float*)d_in[20];
    const float* out_g     = (const float*)d_in[21];
    const float* out_b     = (const float*)d_in[22];
    const float* Wout      = (const float*)d_in[23];
    const float* bout      = (const float*)d_in[24];

    const long NTOK = (long)B_ * T_;  // 8192
    float*  xbuf = (float*)d_ws;                         // fp32 residual (8 MB)
    float*  dbuf = xbuf + NTOK * D_;                     // (B,T,H*NB) fp32 (4 MB)
    float2* csb  = (float2*)(dbuf + NTOK * H_ * NB_);    // (B,H,T,NB) cos/sin (8 MB)
    unsigned short* hbuf  = (unsigned short*)(csb + NTOK * H_ * NB_); // LN out bf16
    unsigned short* qb    = hbuf + NTOK * D_;            // (B,H,T,DH) bf16
    unsigned short* kb    = qb + NTOK * D_;
    unsigned short* vt    = kb + NTOK * D_;              // (B,H,DH,T) bf16
    unsigned short* obuf  = vt + NTOK * D_;              // attn out bf16 row-major
    unsigned short* ffbuf = obuf + NTOK * D_;            // FFN mid bf16 (16 MB)
    unsigned short* wqkvt = ffbuf + NTOK * DFF_;         // [2][768][256]
    unsigned short* wot   = wqkvt + 2 * 768 * 256;
    unsigned short* w1t   = wot + 2 * 65536;
    unsigned short* w2t   = w1t + 2 * 262144;
    unsigned short* woutt = w2t + 2 * 262144;
    // total ~60 MB

    wt_kernel<<<1664, 256, 0, stream>>>(Wq, Wk, Wv, Wo, W1, W2, Wout,
                                        wqkvt, wot, w1t, w2t, woutt);
    embed_kernel<<<NTOK, 256, 0, stream>>>(tokens, token_emb, w_in, w_out, xbuf, dbuf);
    cumsum_kernel<<<B_ * H_ * NB_, 256, 0, stream>>>(dbuf, omega, csb);

    for (int l = 0; l < NL_; ++l) {
        ln_kernel<<<NTOK, 256, 0, stream>>>(xbuf, ln1_g + l * D_, ln1_b + l * D_, hbuf);
        gemm_qkv<<<dim3(6, 64), 256, 0, stream>>>(
            hbuf, wqkvt + (long)l * 196608, bq + l * D_, bk + l * D_, bv + l * D_,
            csb, qb, kb, vt);
        attn_mfma<<<512, 256, 0, stream>>>(qb, kb, vt, obuf);
        gemm_std<64><<<dim3(4, 64), 256, 0, stream>>>(
            obuf, wot + (long)l * 65536, bo + l * D_, xbuf, xbuf, nullptr,
            D_, D_, 0);
        ln_kernel<<<NTOK, 256, 0, stream>>>(xbuf, ln2_g + l * D_, ln2_b + l * D_, hbuf);
        gemm_std<128><<<dim3(8, 64), 256, 0, stream>>>(
            hbuf, w1t + (long)l * 262144, b1 + l * DFF_, nullptr, nullptr, ffbuf,
            DFF_, D_, 1);
        gemm_std<64><<<dim3(4, 64), 256, 0, stream>>>(
            ffbuf, w2t + (long)l * 262144, b2 + l * D_, xbuf, xbuf, nullptr,
            D_, DFF_, 0);
    }

    ln_kernel<<<NTOK, 256, 0, stream>>>(xbuf, out_g, out_b, hbuf);
    gemm_std<128><<<dim3(4, 64), 256, 0, stream>>>(
        hbuf, woutt, bout, nullptr, (float*)d_out, nullptr,
        V_, D_, 0);
}